// Round 3
// baseline (271.755 us; speedup 1.0000x reference)
//
#include <hip/hip_runtime.h>

// B=4, N=10, C=256, Lq=Ls=1024, K=5, G=2.  TQ=64, TS=32.  fp16 MFMA path.
#define CQ_ELEMS (4 * 256 * 1024)
#define CS_ELEMS (10 * 256 * 1024)
#define OUT2_OFF 2097152

typedef __attribute__((ext_vector_type(8))) _Float16 f16x8;
typedef __attribute__((ext_vector_type(4))) float f32x4;

// ws layout (bytes): [0..255] float means[2];
//   Sh[n][s][c] fp16, Sv[n][c][s] fp16, Qt[b][q][c] fp16
#define WS_SH 256
#define SH_ELEMS (10 * 1024 * 256)
#define SV_ELEMS (10 * 256 * 1024)

// direct global->LDS DMA, 16 B per lane; LDS dest = wave-uniform base + lane*16
__device__ __forceinline__ void gload_lds16(const unsigned short* g, unsigned short* l) {
    __builtin_amdgcn_global_load_lds(
        (const __attribute__((address_space(1))) void*)g,
        (__attribute__((address_space(3))) void*)l, 16, 0, 0);
}

// ---------------------------------------------------------------------------
__global__ __launch_bounds__(256) void means_kernel(const float* __restrict__ q,
                                                    const float* __restrict__ s,
                                                    float* __restrict__ ws) {
    const int tid = blockIdx.x * 256 + threadIdx.x;
    const int stride = gridDim.x * 256;
    float sq = 0.f, ss = 0.f;
    const float4* q4 = (const float4*)q;
    const float4* s4 = (const float4*)s;
    for (int i = tid; i < CQ_ELEMS / 4; i += stride) {
        float4 v = q4[i];
        sq += (v.x + v.y) + (v.z + v.w);
    }
    for (int i = tid; i < CS_ELEMS / 4; i += stride) {
        float4 v = s4[i];
        ss += (v.x + v.y) + (v.z + v.w);
    }
#pragma unroll
    for (int off = 32; off > 0; off >>= 1) {
        sq += __shfl_down(sq, off, 64);
        ss += __shfl_down(ss, off, 64);
    }
    __shared__ float redq[4], reds[4];
    const int lane = threadIdx.x & 63, wid = threadIdx.x >> 6;
    if (lane == 0) { redq[wid] = sq; reds[wid] = ss; }
    __syncthreads();
    if (threadIdx.x == 0) {
        atomicAdd(&ws[0], (redq[0] + redq[1]) + (redq[2] + redq[3]));
        atomicAdd(&ws[1], (reds[0] + reds[1]) + (reds[2] + reds[3]));
    }
}

// ---------------------------------------------------------------------------
// Centered fp16 conversion.  z<10: S -> Sv [c][s] + Sh [s][c] + zero out2.
// z>=10: Q -> q_out (fp32, both g-copies) + Qt [q][c].
// ---------------------------------------------------------------------------
__global__ __launch_bounds__(256) void convert_kernel(const float* __restrict__ Q,
                                                      const float* __restrict__ S,
                                                      const float* __restrict__ ws,
                                                      unsigned short* __restrict__ sh,
                                                      unsigned short* __restrict__ sv,
                                                      unsigned short* __restrict__ qt,
                                                      float* __restrict__ out) {
    __shared__ unsigned short Th[32][40];
    const int t = threadIdx.x;
    const int x0 = blockIdx.x << 5;   // s (or q) tile base
    const int c0 = blockIdx.y << 5;   // c tile base
    const int z = blockIdx.z;

    const int cl = t >> 3, x4 = (t & 7) << 2;

    if (z < 10) {
        const int n = z;
        const float ms = ws[1] * (1.0f / (float)CS_ELEMS);
        float4 v = *(const float4*)(S + ((size_t)(n * 256 + c0 + cl)) * 1024 + x0 + x4);
        float x[4] = {v.x - ms, v.y - ms, v.z - ms, v.w - ms};
        unsigned short hb[4];
#pragma unroll
        for (int j = 0; j < 4; ++j) {
            _Float16 h = (_Float16)x[j];
            hb[j] = __builtin_bit_cast(unsigned short, h);
            Th[cl][x4 + j] = hb[j];
        }
        *(ushort4*)(sv + ((size_t)(n * 256 + c0 + cl)) * 1024 + x0 + x4) =
            make_ushort4(hb[0], hb[1], hb[2], hb[3]);
        // zero the atomically-accumulated 'aligned' half of d_out (8 MB over 2560 blocks)
        {
            const int lin = (z * 8 + blockIdx.y) * 32 + blockIdx.x;
            const int gid = lin * 256 + t;
            if (gid < 524288) ((int4*)(out + OUT2_OFF))[gid] = make_int4(0, 0, 0, 0);
        }
        __syncthreads();
        const int sl = t >> 3, c4 = (t & 7) << 2;
        *(ushort4*)(sh + ((size_t)(n * 1024 + x0 + sl)) * 256 + c0 + c4) =
            make_ushort4(Th[c4 + 0][sl], Th[c4 + 1][sl], Th[c4 + 2][sl], Th[c4 + 3][sl]);
    } else {
        const int b = z - 10;
        const float mq = ws[0] * (1.0f / (float)CQ_ELEMS);
        float4 v = *(const float4*)(Q + ((size_t)(b * 256 + c0 + cl)) * 1024 + x0 + x4);
        v.x -= mq; v.y -= mq; v.z -= mq; v.w -= mq;
        float* o = out + ((size_t)(b * 2) * 256 + (c0 + cl)) * 1024 + x0 + x4;
        *(float4*)o = v;
        *(float4*)(o + 256 * 1024) = v;
        float x[4] = {v.x, v.y, v.z, v.w};
#pragma unroll
        for (int j = 0; j < 4; ++j) {
            _Float16 h = (_Float16)x[j];
            Th[cl][x4 + j] = __builtin_bit_cast(unsigned short, h);
        }
        __syncthreads();
        const int ql = t >> 3, c4 = (t & 7) << 2;
        *(ushort4*)(qt + ((size_t)(b * 1024 + x0 + ql)) * 256 + c0 + c4) =
            make_ushort4(Th[c4 + 0][ql], Th[c4 + 1][ql], Th[c4 + 2][ql], Th[c4 + 3][ql]);
    }
}

// ---------------------------------------------------------------------------
// Fused flash attention, fp16 MFMA, 2-phase pipelined DMA staging.
// Block = (64-q tile, bn pair), 4 waves.
//
// s1 (2 x 16 KB, double-buffered): frag-major QK^T B-tiles.  slot16
//   p = (f*2+nt)*64 + quad*16 + l16 holds Sh[s0 + 2*l16 + nt][f*32 + quad*8 .. +7].
//   Read by ALL waves -> cross-wave, staged one tile ahead, drained by the
//   end-of-iteration __syncthreads (vmcnt(0)).
// s2 (16 KB, single-buffered): V^T[c][s] chunks.  Wave w stages AND reads only
//   slots [2048w, 2048w+2047] -> per-wave PRIVATE: no barrier needed, only a
//   per-wave counted s_waitcnt vmcnt(4) before the PV fragment reads (the 4
//   s1[t+1] loads, issued after the 4 s2 loads, stay in flight across it).
// pb: P [q][s] 80 B rows; alpha at cols 32-33.
//
// Row-sum is folded into PV as a ones-channel MFMA (Lsum), so the softmax
// phase has only the rowmax shuffle tree; l_run bookkeeping and the epilogue
// lfin publish are gone.  Per iteration: 2 barriers (one lgkm-only raw
// s_barrier at P-publish, one full __syncthreads at end), one vmcnt(0) drain.
// ---------------------------------------------------------------------------
union __align__(16) SMem {
    struct {
        unsigned short s1[2][8192];  // 32 KB
        unsigned short s2[8192];     // 16 KB
        unsigned short pb[64][40];   // 5 KB (cols 32-33: alpha float)
    } st;
    float epi[2][64][68];            // 34816 B, aliases s1 (+ part of s2) at epilogue
};

__global__ __launch_bounds__(256, 3) void attn_kernel(const unsigned short* __restrict__ qt,
                                                      const unsigned short* __restrict__ sh,
                                                      const unsigned short* __restrict__ sv,
                                                      float* __restrict__ out) {
    __shared__ SMem sm;

    const int t = threadIdx.x;
    const int w = t >> 6;
    const int lane = t & 63;
    const int quad = lane >> 4;
    const int l16 = lane & 15;

    const int q0 = blockIdx.x << 6;   // 16 q-tiles
    const int bn = blockIdx.y;        // 40
    const int b = bn / 10;
    const int n = bn - b * 10;
    const int g = n / 5;

    const unsigned short* __restrict__ Shn = sh + (size_t)n * (1024 * 256);
    const unsigned short* __restrict__ Svn = sv + (size_t)n * (256 * 1024);

    // ---- Q A-frags: wave w owns q rows q0+16w .. +15 ----
    f16x8 qf[8];
    {
        const unsigned short* qp = qt + (size_t)(b * 1024 + q0 + 16 * w + l16) * 256 + quad * 8;
#pragma unroll
        for (int f = 0; f < 8; ++f)
            qf[f] = *(const f16x8*)(qp + f * 32);
    }

    // ones A-frag for the row-sum channel
    f16x8 onesA;
#pragma unroll
    for (int j = 0; j < 8; ++j) onesA[j] = (_Float16)1.0f;

    f32x4 O[4][4];   // O^T: c = 64w+16mt+4quad+r, q = 16nt+l16
#pragma unroll
    for (int mt = 0; mt < 4; ++mt)
#pragma unroll
        for (int nt = 0; nt < 4; ++nt) O[mt][nt] = (f32x4){0.f, 0.f, 0.f, 0.f};

    f32x4 Lsum[4];   // row-sum channel: Lsum[nt][*] = sum_s P[q=16nt+l16][s]
#pragma unroll
    for (int nt = 0; nt < 4; ++nt) Lsum[nt] = (f32x4){0.f, 0.f, 0.f, 0.f};

    float m_run[4];
#pragma unroll
    for (int r = 0; r < 4; ++r) m_run[r] = -1e30f;

    // ---- prologue: stage s1 tile 0 into buffer 0 ----
#pragma unroll
    for (int j = 0; j < 4; ++j) {
        const int fidx = 4 * w + j;
        const unsigned short* g1 = Shn +
            (size_t)(2 * l16 + (fidx & 1)) * 256 + (fidx >> 1) * 32 + quad * 8;
        gload_lds16(g1, &sm.st.s1[0][fidx * 512]);
    }
    __syncthreads();   // drains vmcnt(0): tile 0 ready

    int cur = 0;
    for (int s0i = 0; s0i < 32; ++s0i) {
        const int s0 = s0i << 5;

        // ---- issue V tile t into s2 (own-wave private region; its previous
        //      contents were consumed by this wave's PV before the last barrier)
#pragma unroll
        for (int j = 0; j < 4; ++j) {
            const int fidx = 4 * w + j;
            const unsigned short* g2 = Svn +
                (size_t)(w * 64 + j * 16 + (lane >> 2)) * 1024 + s0 + ((lane & 3) ^ quad) * 8;
            gload_lds16(g2, &sm.st.s2[fidx * 512]);
        }
        // ---- issue s1 tile t+1 into the other buffer (wraps at t=31; the
        //      wrapped tile is never read -- keeps vmcnt counting uniform)
        {
            const int s0n = ((s0i + 1) & 31) << 5;
#pragma unroll
            for (int j = 0; j < 4; ++j) {
                const int fidx = 4 * w + j;
                const unsigned short* g1 = Shn +
                    (size_t)(s0n + 2 * l16 + (fidx & 1)) * 256 + (fidx >> 1) * 32 + quad * 8;
                gload_lds16(g1, &sm.st.s1[cur ^ 1][fidx * 512]);
            }
        }

        // ---- QK^T from s1[cur]: sim[16q x 32s] ----
        f32x4 sim0 = (f32x4){0.f, 0.f, 0.f, 0.f};
        f32x4 sim1 = (f32x4){0.f, 0.f, 0.f, 0.f};
        __builtin_amdgcn_s_setprio(1);
#pragma unroll
        for (int f = 0; f < 8; ++f) {
            const unsigned short* base = &sm.st.s1[cur][f * 1024 + quad * 128 + l16 * 8];
            f16x8 b0 = *(const f16x8*)base;           // nt=0: true s = 2*l16
            f16x8 b1 = *(const f16x8*)(base + 512);   // nt=1: true s = 2*l16+1
            sim0 = __builtin_amdgcn_mfma_f32_16x16x32_f16(qf[f], b0, sim0, 0, 0, 0);
            sim1 = __builtin_amdgcn_mfma_f32_16x16x32_f16(qf[f], b1, sim1, 0, 0, 0);
        }
        __builtin_amdgcn_s_setprio(0);

        // ---- online softmax, max only (rows q = 16w+4quad+r; reduce over l16) ----
        float rowmax[4];
#pragma unroll
        for (int r = 0; r < 4; ++r) rowmax[r] = fmaxf(sim0[r], sim1[r]);
#pragma unroll
        for (int off = 1; off <= 8; off <<= 1)
#pragma unroll
            for (int r = 0; r < 4; ++r)
                rowmax[r] = fmaxf(rowmax[r], __shfl_xor(rowmax[r], off, 64));

        float al[4], pv0[4], pv1[4];
#pragma unroll
        for (int r = 0; r < 4; ++r) {
            const float mn = fmaxf(m_run[r], rowmax[r]);
            al[r] = __expf(m_run[r] - mn);
            m_run[r] = mn;
            pv0[r] = __expf(sim0[r] - mn);
            pv1[r] = __expf(sim1[r] - mn);
        }

        // ---- publish P (fp16 pairs, b32) and alpha (pb cols 32-33) ----
#pragma unroll
        for (int r = 0; r < 4; ++r) {
            union { _Float16 h[2]; unsigned u; } pk;
            pk.h[0] = (_Float16)pv0[r];
            pk.h[1] = (_Float16)pv1[r];
            *(unsigned*)&sm.st.pb[16 * w + 4 * quad + r][l16 * 2] = pk.u;
        }
        if (l16 == 0) {
#pragma unroll
            for (int r = 0; r < 4; ++r)
                *(float*)&sm.st.pb[16 * w + 4 * quad + r][32] = al[r];
        }
        // lgkm-only barrier: drains our LDS writes, leaves the 8 DMA loads in flight
        asm volatile("s_waitcnt lgkmcnt(0)" ::: "memory");
        __builtin_amdgcn_s_barrier();
        __builtin_amdgcn_sched_barrier(0);

        // ---- rescale O^T and Lsum by alpha ----
#pragma unroll
        for (int nt = 0; nt < 4; ++nt) {
            const float a = *(const float*)&sm.st.pb[16 * nt + l16][32];
#pragma unroll
            for (int mt = 0; mt < 4; ++mt) {
                O[mt][nt][0] *= a; O[mt][nt][1] *= a; O[mt][nt][2] *= a; O[mt][nt][3] *= a;
            }
            Lsum[nt][0] *= a; Lsum[nt][1] *= a; Lsum[nt][2] *= a; Lsum[nt][3] *= a;
        }

        // ---- wait for our 4 s2 loads (oldest of the 8 outstanding); the 4
        //      s1[t+1] loads keep flying until the end-of-iteration barrier ----
        asm volatile("s_waitcnt vmcnt(4)" ::: "memory");
        __builtin_amdgcn_sched_barrier(0);

        // ---- O^T += V^T * P^T;  Lsum += ones * P^T ----
        f16x8 vf[4], pf[4];
#pragma unroll
        for (int mt = 0; mt < 4; ++mt) {
            const int c = 64 * w + 16 * mt + l16;
            const int p = c * 4 + (quad ^ ((l16 >> 2) & 3));
            vf[mt] = *(const f16x8*)&sm.st.s2[p * 8];
        }
#pragma unroll
        for (int nt = 0; nt < 4; ++nt)
            pf[nt] = *(const f16x8*)&sm.st.pb[16 * nt + l16][quad * 8];
        __builtin_amdgcn_s_setprio(1);
#pragma unroll
        for (int mt = 0; mt < 4; ++mt)
#pragma unroll
            for (int nt = 0; nt < 4; ++nt)
                O[mt][nt] = __builtin_amdgcn_mfma_f32_16x16x32_f16(vf[mt], pf[nt], O[mt][nt], 0, 0, 0);
#pragma unroll
        for (int nt = 0; nt < 4; ++nt)
            Lsum[nt] = __builtin_amdgcn_mfma_f32_16x16x32_f16(onesA, pf[nt], Lsum[nt], 0, 0, 0);
        __builtin_amdgcn_s_setprio(0);

        __syncthreads();   // vmcnt(0): s1[t+1] ready; guards pb + s2 reuse
        cur ^= 1;
    }

    // ---- epilogue: denominator is in registers (Lsum), no LDS publish ----
    float linv[4];
#pragma unroll
    for (int nt = 0; nt < 4; ++nt)
        linv[nt] = 0.2f / Lsum[nt][0];

    float* __restrict__ out2 = out + OUT2_OFF + (size_t)((g << 2) + b) * (256 * 1024);

#pragma unroll
    for (int h = 0; h < 2; ++h) {
        if ((w >> 1) == h) {
            const int we = w & 1;
#pragma unroll
            for (int mt = 0; mt < 4; ++mt)
#pragma unroll
                for (int nt = 0; nt < 4; ++nt)
#pragma unroll
                    for (int r = 0; r < 4; ++r)
                        sm.epi[we][16 * mt + 4 * quad + r][16 * nt + l16] = O[mt][nt][r] * linv[nt];
        }
        __syncthreads();
#pragma unroll 4
        for (int i = 0; i < 32; ++i) {
            const int ro = w * 32 + i;   // 0..127 -> c = 128h + ro
            const float v = sm.epi[ro >> 6][ro & 63][lane];
            atomicAdd(out2 + (size_t)(h * 128 + ro) * 1024 + q0 + lane, v);
        }
        __syncthreads();
    }
}

// ---------------------------------------------------------------------------
extern "C" void kernel_launch(void* const* d_in, const int* in_sizes, int n_in,
                              void* d_out, int out_size, void* d_ws, size_t ws_size,
                              hipStream_t stream) {
    const float* q = (const float*)d_in[0];
    const float* s = (const float*)d_in[1];
    float* out = (float*)d_out;
    float* ws = (float*)d_ws;
    unsigned short* sh = (unsigned short*)((char*)d_ws + WS_SH);
    unsigned short* sv = sh + SH_ELEMS;
    unsigned short* qt = sv + SV_ELEMS;

    hipMemsetAsync(d_ws, 0, 2 * sizeof(float), stream);

    means_kernel<<<256, 256, 0, stream>>>(q, s, ws);
    convert_kernel<<<dim3(32, 8, 14), 256, 0, stream>>>(q, s, ws, sh, sv, qt, out);
    attn_kernel<<<dim3(16, 40), 256, 0, stream>>>(qt, sh, sv, out);
}

// Round 5
// 215.211 us; speedup vs baseline: 1.2627x; 1.2627x over previous
//
#include <hip/hip_runtime.h>

// B=4, N=10, C=256, Lq=Ls=1024, K=5, G=2.  TQ=64, TS=32.  fp16 MFMA path.
#define CQ_ELEMS (4 * 256 * 1024)
#define CS_ELEMS (10 * 256 * 1024)
#define OUT2_OFF 2097152

typedef __attribute__((ext_vector_type(8))) _Float16 f16x8;
typedef __attribute__((ext_vector_type(4))) float f32x4;

// ws layout (bytes): [0..255] float means[2];
//   Sh[n][s][c] fp16, Sv[n][c][s] fp16, Qt[b][q][c] fp16
#define WS_SH 256
#define SH_ELEMS (10 * 1024 * 256)
#define SV_ELEMS (10 * 256 * 1024)

// direct global->LDS DMA, 16 B per lane; LDS dest = wave-uniform base + lane*16
__device__ __forceinline__ void gload_lds16(const unsigned short* g, unsigned short* l) {
    __builtin_amdgcn_global_load_lds(
        (const __attribute__((address_space(1))) void*)g,
        (__attribute__((address_space(3))) void*)l, 16, 0, 0);
}

// ---------------------------------------------------------------------------
__global__ __launch_bounds__(256) void means_kernel(const float* __restrict__ q,
                                                    const float* __restrict__ s,
                                                    float* __restrict__ ws) {
    const int tid = blockIdx.x * 256 + threadIdx.x;
    const int stride = gridDim.x * 256;
    float sq = 0.f, ss = 0.f;
    const float4* q4 = (const float4*)q;
    const float4* s4 = (const float4*)s;
    for (int i = tid; i < CQ_ELEMS / 4; i += stride) {
        float4 v = q4[i];
        sq += (v.x + v.y) + (v.z + v.w);
    }
    for (int i = tid; i < CS_ELEMS / 4; i += stride) {
        float4 v = s4[i];
        ss += (v.x + v.y) + (v.z + v.w);
    }
#pragma unroll
    for (int off = 32; off > 0; off >>= 1) {
        sq += __shfl_down(sq, off, 64);
        ss += __shfl_down(ss, off, 64);
    }
    __shared__ float redq[4], reds[4];
    const int lane = threadIdx.x & 63, wid = threadIdx.x >> 6;
    if (lane == 0) { redq[wid] = sq; reds[wid] = ss; }
    __syncthreads();
    if (threadIdx.x == 0) {
        atomicAdd(&ws[0], (redq[0] + redq[1]) + (redq[2] + redq[3]));
        atomicAdd(&ws[1], (reds[0] + reds[1]) + (reds[2] + reds[3]));
    }
}

// ---------------------------------------------------------------------------
// Centered fp16 conversion.  z<10: S -> Sv [c][s] + Sh [s][c] + zero out2.
// z>=10: Q -> q_out (fp32, both g-copies) + Qt [q][c].
// ---------------------------------------------------------------------------
__global__ __launch_bounds__(256) void convert_kernel(const float* __restrict__ Q,
                                                      const float* __restrict__ S,
                                                      const float* __restrict__ ws,
                                                      unsigned short* __restrict__ sh,
                                                      unsigned short* __restrict__ sv,
                                                      unsigned short* __restrict__ qt,
                                                      float* __restrict__ out) {
    __shared__ unsigned short Th[32][40];
    const int t = threadIdx.x;
    const int x0 = blockIdx.x << 5;   // s (or q) tile base
    const int c0 = blockIdx.y << 5;   // c tile base
    const int z = blockIdx.z;

    const int cl = t >> 3, x4 = (t & 7) << 2;

    if (z < 10) {
        const int n = z;
        const float ms = ws[1] * (1.0f / (float)CS_ELEMS);
        float4 v = *(const float4*)(S + ((size_t)(n * 256 + c0 + cl)) * 1024 + x0 + x4);
        float x[4] = {v.x - ms, v.y - ms, v.z - ms, v.w - ms};
        unsigned short hb[4];
#pragma unroll
        for (int j = 0; j < 4; ++j) {
            _Float16 h = (_Float16)x[j];
            hb[j] = __builtin_bit_cast(unsigned short, h);
            Th[cl][x4 + j] = hb[j];
        }
        *(ushort4*)(sv + ((size_t)(n * 256 + c0 + cl)) * 1024 + x0 + x4) =
            make_ushort4(hb[0], hb[1], hb[2], hb[3]);
        // zero the atomically-accumulated 'aligned' half of d_out (8 MB over 2560 blocks)
        {
            const int lin = (z * 8 + blockIdx.y) * 32 + blockIdx.x;
            const int gid = lin * 256 + t;
            if (gid < 524288) ((int4*)(out + OUT2_OFF))[gid] = make_int4(0, 0, 0, 0);
        }
        __syncthreads();
        const int sl = t >> 3, c4 = (t & 7) << 2;
        *(ushort4*)(sh + ((size_t)(n * 1024 + x0 + sl)) * 256 + c0 + c4) =
            make_ushort4(Th[c4 + 0][sl], Th[c4 + 1][sl], Th[c4 + 2][sl], Th[c4 + 3][sl]);
    } else {
        const int b = z - 10;
        const float mq = ws[0] * (1.0f / (float)CQ_ELEMS);
        float4 v = *(const float4*)(Q + ((size_t)(b * 256 + c0 + cl)) * 1024 + x0 + x4);
        v.x -= mq; v.y -= mq; v.z -= mq; v.w -= mq;
        float* o = out + ((size_t)(b * 2) * 256 + (c0 + cl)) * 1024 + x0 + x4;
        *(float4*)o = v;
        *(float4*)(o + 256 * 1024) = v;
        float x[4] = {v.x, v.y, v.z, v.w};
#pragma unroll
        for (int j = 0; j < 4; ++j) {
            _Float16 h = (_Float16)x[j];
            Th[cl][x4 + j] = __builtin_bit_cast(unsigned short, h);
        }
        __syncthreads();
        const int ql = t >> 3, c4 = (t & 7) << 2;
        *(ushort4*)(qt + ((size_t)(b * 1024 + x0 + ql)) * 256 + c0 + c4) =
            make_ushort4(Th[c4 + 0][ql], Th[c4 + 1][ql], Th[c4 + 2][ql], Th[c4 + 3][ql]);
    }
}

// ---------------------------------------------------------------------------
// Fused flash attention, fp16 MFMA.  Block = (64-q tile, bn pair), 4 waves.
//
// Sync skeleton = the verified 124 us baseline (plain __syncthreads only; no
// raw barriers / counted vmcnt -- R3 showed those destroy L2 reuse timing:
// stream FETCH 9 -> 39 MB, occupancy -1/3, dur +56%).  Two changes vs baseline:
//
// 1) V is NOT staged in LDS.  Wave w's PV A-frags are 4 global_load_dwordx4
//    per iteration straight from Sv (L2-resident stream: baseline stream
//    fetch was ~9 MB total).  Issued at loop top, consumed after the P
//    barrier -> QK^T+softmax covers the L2 latency, in registers.
// 2) s1 (QK^T B-tiles) double-buffered in the LDS freed by s2: tile t+1's
//    DMA is issued at loop top and drained by the P-publish __syncthreads.
//    LDS total 37888 B -- identical footprint to the baseline.
//
// s1 slot16 p = (f*2+nt)*64 + quad*16 + l16 holds
//   Sh[s0 + 2*l16 + nt][f*32 + quad*8 .. +7]; frag reads are consecutive-lane
//   16 B -> conflict-free.
// pb: P [q][s] 80 B rows; alpha at cols 32-33.
// Row-sum folded into PV as a ones-channel MFMA (Lsum): softmax has only the
// rowmax shuffle tree; no l_run, no epilogue lfin publish.
// 2 barriers per iteration (baseline had 3).
// ---------------------------------------------------------------------------
union __align__(16) SMem {
    struct {
        unsigned short s1[2][8192];  // 32 KB, double-buffered
        unsigned short pb[64][40];   // 5 KB (cols 32-33: alpha float)
    } st;
    float epi[2][64][68];            // 34816 B, aliases s1 + pb[0..25] at epilogue
};

__global__ __launch_bounds__(256, 3) void attn_kernel(const unsigned short* __restrict__ qt,
                                                      const unsigned short* __restrict__ sh,
                                                      const unsigned short* __restrict__ sv,
                                                      float* __restrict__ out) {
    __shared__ SMem sm;

    const int t = threadIdx.x;
    const int w = t >> 6;
    const int lane = t & 63;
    const int quad = lane >> 4;
    const int l16 = lane & 15;

    const int q0 = blockIdx.x << 6;   // 16 q-tiles
    const int bn = blockIdx.y;        // 40
    const int b = bn / 10;
    const int n = bn - b * 10;
    const int g = n / 5;

    const unsigned short* __restrict__ Shn = sh + (size_t)n * (1024 * 256);
    const unsigned short* __restrict__ Svn = sv + (size_t)n * (256 * 1024);

    // ---- Q A-frags: wave w owns q rows q0+16w .. +15 ----
    f16x8 qf[8];
    {
        const unsigned short* qp = qt + (size_t)(b * 1024 + q0 + 16 * w + l16) * 256 + quad * 8;
#pragma unroll
        for (int f = 0; f < 8; ++f)
            qf[f] = *(const f16x8*)(qp + f * 32);
    }

    // ones A-frag for the row-sum channel
    f16x8 onesA;
#pragma unroll
    for (int j = 0; j < 8; ++j) onesA[j] = (_Float16)1.0f;

    f32x4 O[4][4];   // O^T: c = 64w+16mt+4quad+r, q = 16nt+l16
#pragma unroll
    for (int mt = 0; mt < 4; ++mt)
#pragma unroll
        for (int nt = 0; nt < 4; ++nt) O[mt][nt] = (f32x4){0.f, 0.f, 0.f, 0.f};

    f32x4 Lsum[4];   // row-sum channel: Lsum[nt][*] = sum_s P[q=16nt+l16][s]
#pragma unroll
    for (int nt = 0; nt < 4; ++nt) Lsum[nt] = (f32x4){0.f, 0.f, 0.f, 0.f};

    float m_run[4];
#pragma unroll
    for (int r = 0; r < 4; ++r) m_run[r] = -1e30f;

    // ---- prologue: issue s1 tile 0 into buffer 0 (drained by first loop barrier) ----
#pragma unroll
    for (int j = 0; j < 4; ++j) {
        const int fidx = 4 * w + j;
        const unsigned short* g1 = Shn +
            (size_t)(2 * l16 + (fidx & 1)) * 256 + (fidx >> 1) * 32 + quad * 8;
        gload_lds16(g1, &sm.st.s1[0][fidx * 512]);
    }

    int cur = 0;
    for (int s0i = 0; s0i < 32; ++s0i) {
        const int s0 = s0i << 5;

        // B: drains all vmem -> s1[cur] = tile t ready; pb safe to overwrite
        __syncthreads();

        // ---- issue s1 tile t+1 into the other buffer (wraps at t=31; the
        //      wrapped tile is never read) ----
        {
            const int s0n = ((s0i + 1) & 31) << 5;
#pragma unroll
            for (int j = 0; j < 4; ++j) {
                const int fidx = 4 * w + j;
                const unsigned short* g1 = Shn +
                    (size_t)(s0n + 2 * l16 + (fidx & 1)) * 256 + (fidx >> 1) * 32 + quad * 8;
                gload_lds16(g1, &sm.st.s1[cur ^ 1][fidx * 512]);
            }
        }

        // ---- V A-frags straight from global (L2-hot); used after barrier C,
        //      so QK^T + softmax covers the load latency ----
        f16x8 vf[4];
#pragma unroll
        for (int mt = 0; mt < 4; ++mt)
            vf[mt] = *(const f16x8*)(Svn + (size_t)(64 * w + 16 * mt + l16) * 1024 + s0 + quad * 8);

        // ---- QK^T from s1[cur]: sim[16q x 32s] ----
        f32x4 sim0 = (f32x4){0.f, 0.f, 0.f, 0.f};
        f32x4 sim1 = (f32x4){0.f, 0.f, 0.f, 0.f};
        __builtin_amdgcn_s_setprio(1);
#pragma unroll
        for (int f = 0; f < 8; ++f) {
            const unsigned short* base = &sm.st.s1[cur][f * 1024 + quad * 128 + l16 * 8];
            f16x8 b0 = *(const f16x8*)base;           // nt=0: true s = 2*l16
            f16x8 b1 = *(const f16x8*)(base + 512);   // nt=1: true s = 2*l16+1
            sim0 = __builtin_amdgcn_mfma_f32_16x16x32_f16(qf[f], b0, sim0, 0, 0, 0);
            sim1 = __builtin_amdgcn_mfma_f32_16x16x32_f16(qf[f], b1, sim1, 0, 0, 0);
        }
        __builtin_amdgcn_s_setprio(0);

        // ---- online softmax, max only (rows q = 16w+4quad+r; reduce over l16) ----
        float rowmax[4];
#pragma unroll
        for (int r = 0; r < 4; ++r) rowmax[r] = fmaxf(sim0[r], sim1[r]);
#pragma unroll
        for (int off = 1; off <= 8; off <<= 1)
#pragma unroll
            for (int r = 0; r < 4; ++r)
                rowmax[r] = fmaxf(rowmax[r], __shfl_xor(rowmax[r], off, 64));

        float al[4], pv0[4], pv1[4];
#pragma unroll
        for (int r = 0; r < 4; ++r) {
            const float mn = fmaxf(m_run[r], rowmax[r]);
            al[r] = __expf(m_run[r] - mn);
            m_run[r] = mn;
            pv0[r] = __expf(sim0[r] - mn);
            pv1[r] = __expf(sim1[r] - mn);
        }

        // ---- publish P (fp16 pairs, b32) and alpha (pb cols 32-33) ----
#pragma unroll
        for (int r = 0; r < 4; ++r) {
            union { _Float16 h[2]; unsigned u; } pk;
            pk.h[0] = (_Float16)pv0[r];
            pk.h[1] = (_Float16)pv1[r];
            *(unsigned*)&sm.st.pb[16 * w + 4 * quad + r][l16 * 2] = pk.u;
        }
        if (l16 == 0) {
#pragma unroll
            for (int r = 0; r < 4; ++r)
                *(float*)&sm.st.pb[16 * w + 4 * quad + r][32] = al[r];
        }

        // C: P ready (also drains the vf loads and most of the s1 prefetch)
        __syncthreads();

        // ---- rescale O^T and Lsum by alpha ----
#pragma unroll
        for (int nt = 0; nt < 4; ++nt) {
            const float a = *(const float*)&sm.st.pb[16 * nt + l16][32];
#pragma unroll
            for (int mt = 0; mt < 4; ++mt) {
                O[mt][nt][0] *= a; O[mt][nt][1] *= a; O[mt][nt][2] *= a; O[mt][nt][3] *= a;
            }
            Lsum[nt][0] *= a; Lsum[nt][1] *= a; Lsum[nt][2] *= a; Lsum[nt][3] *= a;
        }

        // ---- O^T += V^T * P^T;  Lsum += ones * P^T ----
        f16x8 pf[4];
#pragma unroll
        for (int nt = 0; nt < 4; ++nt)
            pf[nt] = *(const f16x8*)&sm.st.pb[16 * nt + l16][quad * 8];
        __builtin_amdgcn_s_setprio(1);
#pragma unroll
        for (int mt = 0; mt < 4; ++mt)
#pragma unroll
            for (int nt = 0; nt < 4; ++nt)
                O[mt][nt] = __builtin_amdgcn_mfma_f32_16x16x32_f16(vf[mt], pf[nt], O[mt][nt], 0, 0, 0);
#pragma unroll
        for (int nt = 0; nt < 4; ++nt)
            Lsum[nt] = __builtin_amdgcn_mfma_f32_16x16x32_f16(onesA, pf[nt], Lsum[nt], 0, 0, 0);
        __builtin_amdgcn_s_setprio(0);

        cur ^= 1;
    }

    // all final pf reads done before epi writes alias s1/pb
    __syncthreads();

    // ---- epilogue: denominator is in registers (Lsum), no LDS publish ----
    float linv[4];
#pragma unroll
    for (int nt = 0; nt < 4; ++nt)
        linv[nt] = 0.2f / Lsum[nt][0];

    float* __restrict__ out2 = out + OUT2_OFF + (size_t)((g << 2) + b) * (256 * 1024);

#pragma unroll
    for (int h = 0; h < 2; ++h) {
        if ((w >> 1) == h) {
            const int we = w & 1;
#pragma unroll
            for (int mt = 0; mt < 4; ++mt)
#pragma unroll
                for (int nt = 0; nt < 4; ++nt)
#pragma unroll
                    for (int r = 0; r < 4; ++r)
                        sm.epi[we][16 * mt + 4 * quad + r][16 * nt + l16] = O[mt][nt][r] * linv[nt];
        }
        __syncthreads();
#pragma unroll 4
        for (int i = 0; i < 32; ++i) {
            const int ro = w * 32 + i;   // 0..127 -> c = 128h + ro
            const float v = sm.epi[ro >> 6][ro & 63][lane];
            atomicAdd(out2 + (size_t)(h * 128 + ro) * 1024 + q0 + lane, v);
        }
        __syncthreads();
    }
}

// ---------------------------------------------------------------------------
extern "C" void kernel_launch(void* const* d_in, const int* in_sizes, int n_in,
                              void* d_out, int out_size, void* d_ws, size_t ws_size,
                              hipStream_t stream) {
    const float* q = (const float*)d_in[0];
    const float* s = (const float*)d_in[1];
    float* out = (float*)d_out;
    float* ws = (float*)d_ws;
    unsigned short* sh = (unsigned short*)((char*)d_ws + WS_SH);
    unsigned short* sv = sh + SH_ELEMS;
    unsigned short* qt = sv + SV_ELEMS;

    hipMemsetAsync(d_ws, 0, 2 * sizeof(float), stream);

    means_kernel<<<256, 256, 0, stream>>>(q, s, ws);
    convert_kernel<<<dim3(32, 8, 14), 256, 0, stream>>>(q, s, ws, sh, sv, qt, out);
    attn_kernel<<<dim3(16, 40), 256, 0, stream>>>(qt, sh, sv, out);
}